// Round 4
// baseline (413.549 us; speedup 1.0000x reference)
//
#include <hip/hip_runtime.h>

using u16 = unsigned short;
typedef __bf16 bf16x8 __attribute__((ext_vector_type(8)));
typedef u16    u16x8  __attribute__((ext_vector_type(8)));
typedef u16    u16x4  __attribute__((ext_vector_type(4)));
typedef float  f32x4  __attribute__((ext_vector_type(4)));
typedef float  f32x16 __attribute__((ext_vector_type(16)));
typedef unsigned uint4v __attribute__((ext_vector_type(4)));

#define DEV static __device__ __forceinline__

constexpr int NB = 4;          // batch
constexpr int NN = 20000;      // tokens
constexpr int DD = 64;         // model dim
constexpr int KK = 256;        // linformer K
constexpr int ROWS = NB * NN;  // 80000 flat rows

DEV float b2f(u16 u) { union { unsigned i; float f; } c; c.i = ((unsigned)u) << 16; return c.f; }
DEV u16 f2b(float f) {
  union { float f; unsigned i; } c; c.f = f;
  unsigned i = c.i + 0x7FFFu + ((c.i >> 16) & 1u);
  return (u16)(i >> 16);
}
DEV bf16x8 ldb8(const u16* p) { return *reinterpret_cast<const bf16x8*>(p); }
DEV f32x16 mfma32(bf16x8 a, bf16x8 b, f32x16 c) { return __builtin_amdgcn_mfma_f32_32x32x16_bf16(a, b, c, 0, 0, 0); }

// pack two f32 -> one u32 of 2 bf16 (elem0 = lo, elem1 = hi), RNE
DEV unsigned cvtpk(float lo, float hi) {
  unsigned r;
  asm("v_cvt_pk_bf16_f32 %0, %1, %2" : "=v"(r) : "v"(lo), "v"(hi));
  return r;
}
// exchange: a' = [a.lo32 | b.lo32], b' = [a.hi32 | b.hi32]
DEV void swap32(unsigned& a, unsigned& b) {
  auto r = __builtin_amdgcn_permlane32_swap((int)a, (int)b, false, false);
  a = (unsigned)r[0]; b = (unsigned)r[1];
}

// ---------------------------------------------------------------------------
// Merged preamble (no LDS anywhere):
//  [0,2512)      transpose projK/projV -> bf16 [K][N] via column reads
//  [2512,5012)   embed
//  [5012,5076)   weight fragment conversion
//  [5076]        ones fill
__global__ __launch_bounds__(256) void k_pre(
    const float* __restrict__ expr, const float* __restrict__ emb,
    const float* __restrict__ Wq, const float* __restrict__ Wo,
    const float* __restrict__ W1, const float* __restrict__ W2,
    const float* __restrict__ projK, const float* __restrict__ projV,
    u16* __restrict__ wb, u16* __restrict__ pKT, u16* __restrict__ pVT,
    u16* __restrict__ xb, u16* __restrict__ ones) {
  int bid = blockIdx.x;
  int t = threadIdx.x;
  if (bid < 2512) {
    // ---- transpose [L][N][K] f32 -> [L][K][N] bf16, column reads, no LDS.
    int nt = bid % 157, q = bid / 157, kt = q & 3, z = q >> 2;
    int layer = z & 1, pv = z >> 1;
    const float* src = (pv ? projV : projK) + (size_t)layer * NN * KK;
    u16* dst = (pv ? pVT : pKT) + (size_t)layer * KK * NN;
    int k = kt * 64 + (t & 63);
    int n0 = nt * 128 + (t >> 6) * 32;
    if (n0 >= NN) return;  // NN%32==0 -> all-or-nothing per thread
    float v[32];
#pragma unroll
    for (int i = 0; i < 32; ++i) v[i] = src[(size_t)(n0 + i) * KK + k];
    unsigned ov[16];
#pragma unroll
    for (int i2 = 0; i2 < 16; ++i2) ov[i2] = cvtpk(v[2 * i2], v[2 * i2 + 1]);
    u16* drow = dst + (size_t)k * NN + n0;
#pragma unroll
    for (int p = 0; p < 4; ++p) {
      uint4v o; o.x = ov[p * 4 + 0]; o.y = ov[p * 4 + 1]; o.z = ov[p * 4 + 2]; o.w = ov[p * 4 + 3];
      *reinterpret_cast<uint4v*>(&drow[p * 8]) = o;
    }
  } else if (bid < 5012) {
    // ---- embed: x[b,n,d] = emb[n,d]*expr[b,n] -> bf16
    int idx8 = ((bid - 2512) * 256 + t) * 8;
    int b = idx8 / (NN * DD);
    int rem = idx8 - b * (NN * DD);
    int n = rem >> 6, d = rem & 63;
    float4 e0 = *reinterpret_cast<const float4*>(&emb[(n << 6) + d]);
    float4 e1 = *reinterpret_cast<const float4*>(&emb[(n << 6) + d + 4]);
    float s = expr[b * NN + n];
    u16x8 o;
    o[0] = f2b(e0.x * s); o[1] = f2b(e0.y * s); o[2] = f2b(e0.z * s); o[3] = f2b(e0.w * s);
    o[4] = f2b(e1.x * s); o[5] = f2b(e1.y * s); o[6] = f2b(e1.z * s); o[7] = f2b(e1.w * s);
    *reinterpret_cast<u16x8*>(&xb[idx8]) = o;
  } else if (bid < 5076) {
    // ---- weight conversion into MFMA fragment orders
    int b2 = bid - 5012;
    int bx = b2 & 7, m = (b2 >> 3) & 3, l = b2 >> 5;
    int slot = bx * 256 + t;
    u16x8 o;
    if (m <= 1) {
      if (slot >= 512) return;
      int s = slot >> 7, rem = slot & 127;
      int ct = rem >> 6, lane = rem & 63;
      int hi = lane >> 5, lo = lane & 31;
      const float* src = (m == 0 ? Wq : Wo) + l * 4096;
      u16* dst = wb + (m == 0 ? 0 : 8192) + l * 4096;
#pragma unroll
      for (int j = 0; j < 8; ++j) o[j] = f2b(src[(s * 16 + hi * 8 + j) * 64 + ct * 32 + lo]);
      *reinterpret_cast<u16x8*>(&dst[slot * 8]) = o;
    } else if (m == 2) {
      // W1T: A-frag rows = f
      int ftile = slot >> 8, s = (slot >> 6) & 3, lane = slot & 63;
      int hi = lane >> 5, lo = lane & 31;
      const float* src = W1 + l * 16384;
      u16* dst = wb + 16384 + l * 16384;
#pragma unroll
      for (int j = 0; j < 8; ++j) o[j] = f2b(src[(s * 16 + hi * 8 + j) * 256 + ftile * 32 + lo]);
      *reinterpret_cast<u16x8*>(&dst[slot * 8]) = o;
    } else {
      // W2T: A-frag rows = d
      int dtile = slot >> 10, s2 = (slot >> 6) & 15, lane = slot & 63;
      int hi = lane >> 5, lo = lane & 31;
      const float* src = W2 + l * 16384;
      u16* dst = wb + 49152 + l * 16384;
#pragma unroll
      for (int j = 0; j < 8; ++j) o[j] = f2b(src[(s2 * 16 + hi * 8 + j) * 64 + dtile * 32 + lo]);
      *reinterpret_cast<u16x8*>(&dst[slot * 8]) = o;
    }
  } else {
    ones[t] = 0x3F80;  // bf16 1.0, 256 entries
  }
}

// ---------------------------------------------------------------------------
// Merged: [0,625) Q = x @ Wq (round-2-proven GEMM, writes qb);
//         [625,1253) xT transpose (LDS-free column reads).
__global__ __launch_bounds__(256) void k_qxt(
    const u16* __restrict__ x, const u16* __restrict__ WB,
    u16* __restrict__ qb, u16* __restrict__ xT) {
  int bid = blockIdx.x;
  int t = threadIdx.x;
  if (bid < 625) {
    int w = t >> 6, lane = t & 63;
    int lo = lane & 31, hi = lane >> 5;
    int unit = bid * 4 + w;
    bf16x8 wf[4][2];
#pragma unroll
    for (int s = 0; s < 4; ++s)
#pragma unroll
      for (int ct = 0; ct < 2; ++ct) wf[s][ct] = ldb8(&WB[((s * 2 + ct) * 64 + lane) * 8]);
    f32x16 acc[2] = {};
    int r0 = unit * 32;
#pragma unroll
    for (int s = 0; s < 4; ++s) {
      bf16x8 a = ldb8(&x[(size_t)(r0 + lo) * 64 + s * 16 + hi * 8]);
      acc[0] = mfma32(a, wf[s][0], acc[0]);
      acc[1] = mfma32(a, wf[s][1], acc[1]);
    }
#pragma unroll
    for (int reg = 0; reg < 16; ++reg) {
      int row = r0 + (reg & 3) + 8 * (reg >> 2) + 4 * hi;
      qb[(size_t)row * 64 + lo] = f2b(acc[0][reg]);
      qb[(size_t)row * 64 + 32 + lo] = f2b(acc[1][reg]);
    }
  } else {
    int v = bid - 625;
    int nt = v % 157, b = v / 157;
    int d = t & 63;
    int n0 = nt * 128 + (t >> 6) * 32;
    if (n0 >= NN) return;
    const u16* xbp = x + (size_t)b * NN * 64;
    u16 vv[32];
#pragma unroll
    for (int i = 0; i < 32; ++i) vv[i] = xbp[(size_t)(n0 + i) * 64 + d];
    u16* dst = xT + (size_t)b * 64 * NN + (size_t)d * NN + n0;
#pragma unroll
    for (int p = 0; p < 4; ++p) {
      u16x8 o;
#pragma unroll
      for (int j = 0; j < 8; ++j) o[j] = vv[p * 8 + j];
      *reinterpret_cast<u16x8*>(&dst[p * 8]) = o;
    }
  }
}

// ---------------------------------------------------------------------------
// Linformer projection partials, 4x unrolled n-loop for MLP.
// part[proj][b][c][64 d][256 k] = sum_n xT[d][n]*pT[k][n]
__global__ __launch_bounds__(256) void k_proj(
    const u16* __restrict__ xT, const u16* __restrict__ pKT_l, const u16* __restrict__ pVT_l,
    float* __restrict__ part) {
  int c = blockIdx.x, b = blockIdx.y, proj = blockIdx.z;
  const u16* P = proj ? pVT_l : pKT_l;
  int t = threadIdx.x, w = t >> 6, lane = t & 63;
  int lo = lane & 31, hi = lane >> 5;
  int d0 = (w & 1) * 32;
  int kbase = (w >> 1) * 128;
  int n0 = c * 512;
  int rem = NN - n0;
  int steps = (rem < 512 ? rem : 512) >> 4;
  const u16* xr = xT + ((size_t)b * 64 + d0 + lo) * NN;
  f32x16 acc[4] = {};
  int s = 0;
  for (; s + 4 <= steps; s += 4) {
    bf16x8 a[4]; bf16x8 bv[4][4];
#pragma unroll
    for (int u = 0; u < 4; ++u) {
      int nb = n0 + (s + u) * 16 + hi * 8;
      a[u] = ldb8(&xr[nb]);
#pragma unroll
      for (int g = 0; g < 4; ++g) bv[u][g] = ldb8(&P[(size_t)(kbase + g * 32 + lo) * NN + nb]);
    }
#pragma unroll
    for (int u = 0; u < 4; ++u)
#pragma unroll
      for (int g = 0; g < 4; ++g) acc[g] = mfma32(a[u], bv[u][g], acc[g]);
  }
  for (; s < steps; ++s) {
    int nb = n0 + s * 16 + hi * 8;
    bf16x8 a = ldb8(&xr[nb]);
#pragma unroll
    for (int g = 0; g < 4; ++g) acc[g] = mfma32(a, ldb8(&P[(size_t)(kbase + g * 32 + lo) * NN + nb]), acc[g]);
  }
  float* dst = part + ((size_t)(proj * NB + b) * 40 + c) * (64 * 256);
#pragma unroll
  for (int g = 0; g < 4; ++g)
#pragma unroll
    for (int r = 0; r < 16; ++r) {
      int d = d0 + (r & 3) + 8 * (r >> 2) + 4 * hi;
      dst[d * 256 + kbase + g * 32 + lo] = acc[g][r];
    }
}

// ---------------------------------------------------------------------------
// Reduce 40 chunk-partials + apply Wk/Wv. K-side pre-scaled by SCALE*log2e.
__global__ __launch_bounds__(256) void k_p2(
    const float* __restrict__ part, const float* __restrict__ Wk_l, const float* __restrict__ Wv_l,
    u16* __restrict__ kbuf, u16* __restrict__ vT) {
  int ks = blockIdx.x, b = blockIdx.y, proj = blockIdx.z;
  int k0 = ks * 8;
  const float* W = proj ? Wv_l : Wk_l;
  __shared__ float low[64][8];
  int t = threadIdx.x;
  const float* src = part + (size_t)(proj * NB + b) * 40 * (64 * 256);
#pragma unroll
  for (int i = 0; i < 2; ++i) {
    int idx = i * 256 + t;
    int e = idx >> 3, k = idx & 7;
    float s = 0.f;
    for (int cc = 0; cc < 40; ++cc) s += src[(size_t)cc * (64 * 256) + e * 256 + k0 + k];
    low[e][k] = s;
  }
  __syncthreads();
#pragma unroll
  for (int i = 0; i < 2; ++i) {
    int idx = i * 256 + t;
    int d = idx & 63, kk = idx >> 6;
    float a = 0.f;
#pragma unroll
    for (int e = 0; e < 64; ++e) a += low[e][kk] * W[e * 64 + d];
    if (proj == 0) {
      kbuf[((size_t)b * KK + k0 + kk) * 64 + d] = f2b(a * 0.3606737602222409f);
    } else {
      vT[((size_t)b * 64 + d) * KK + k0 + kk] = f2b(a);
    }
  }
}

// ---------------------------------------------------------------------------
// Fused Linformer attention (round-2-proven). Block = 32 queries x 4 heads.
__global__ __launch_bounds__(256) void k_attn(
    const u16* __restrict__ q, const u16* __restrict__ kbuf, const u16* __restrict__ vT,
    const u16* __restrict__ ones, u16* __restrict__ ao) {
  int t = threadIdx.x, h = t >> 6, lane = t & 63;
  int lo = lane & 31, hi = lane >> 5;
  int b = blockIdx.y;
  int n0 = blockIdx.x * 32;
  const u16* qb = q + (size_t)b * NN * 64;
  const u16* kb = kbuf + (size_t)b * KK * 64 + h * 16;
  const u16* vsrc = (lo < 16)
      ? vT + (size_t)b * 64 * KK + (size_t)(h * 16 + lo) * KK
      : ones;
  bf16x8 qf = ldb8(&qb[(size_t)(n0 + lo) * 64 + h * 16 + hi * 8]);
  f32x16 acc = {};
#pragma unroll
  for (int kt = 0; kt < 8; ++kt) {
    bf16x8 kf = ldb8(&kb[(size_t)(kt * 32 + lo) * 64 + hi * 8]);
    f32x16 z = {};
    f32x16 s = mfma32(kf, qf, z);
    float e[16];
#pragma unroll
    for (int r = 0; r < 16; ++r) e[r] = __builtin_amdgcn_exp2f(s[r]);
#pragma unroll
    for (int c = 0; c < 2; ++c) {
      unsigned Aw = cvtpk(e[c * 8 + 0], e[c * 8 + 1]);
      unsigned Bw = cvtpk(e[c * 8 + 2], e[c * 8 + 3]);
      unsigned Cw = cvtpk(e[c * 8 + 4], e[c * 8 + 5]);
      unsigned Dw = cvtpk(e[c * 8 + 6], e[c * 8 + 7]);
      swap32(Aw, Cw);
      swap32(Bw, Dw);
      uint4v pk; pk.x = Aw; pk.y = Bw; pk.z = Cw; pk.w = Dw;
      bf16x8 af = ldb8(&vsrc[kt * 32 + c * 16 + hi * 8]);
      acc = mfma32(af, __builtin_bit_cast(bf16x8, pk), acc);
    }
  }
  float inv = __builtin_amdgcn_rcpf(acc[8]);
  float o[8];
#pragma unroll
  for (int r = 0; r < 8; ++r) o[r] = acc[r] * inv;
  unsigned Aw = cvtpk(o[0], o[1]);
  unsigned Bw = cvtpk(o[2], o[3]);
  unsigned Cw = cvtpk(o[4], o[5]);
  unsigned Dw = cvtpk(o[6], o[7]);
  swap32(Aw, Cw);
  swap32(Bw, Dw);
  uint4v st; st.x = Aw; st.y = Bw; st.z = Cw; st.w = Dw;
  *reinterpret_cast<uint4v*>(&ao[(size_t)b * NN * 64 + (size_t)(n0 + lo) * 64 + h * 16 + hi * 8]) = st;
}

// ---------------------------------------------------------------------------
// Row GEMM out[M,64] = A[M,64] @ W[64,64] + bias + residual + LayerNorm.
__global__ __launch_bounds__(256) void k_oln(
    const u16* __restrict__ A, const u16* __restrict__ WB,
    const float* __restrict__ bias, const u16* __restrict__ res,
    const float* __restrict__ g, const float* __restrict__ be, u16* __restrict__ out) {
  int t = threadIdx.x, w = t >> 6, lane = t & 63;
  int lo = lane & 31, hi = lane >> 5;
  int unit = blockIdx.x * 4 + w;
  bf16x8 wf[4][2];
#pragma unroll
  for (int s = 0; s < 4; ++s)
#pragma unroll
    for (int ct = 0; ct < 2; ++ct) wf[s][ct] = ldb8(&WB[((s * 2 + ct) * 64 + lane) * 8]);
  float bia[2], gg[2], bb[2];
#pragma unroll
  for (int ct = 0; ct < 2; ++ct) {
    bia[ct] = bias[ct * 32 + lo];
    gg[ct] = g[ct * 32 + lo];
    bb[ct] = be[ct * 32 + lo];
  }
  f32x16 acc[2] = {};
  int r0 = unit * 32;
#pragma unroll
  for (int s = 0; s < 4; ++s) {
    bf16x8 a = ldb8(&A[(size_t)(r0 + lo) * 64 + s * 16 + hi * 8]);
    acc[0] = mfma32(a, wf[s][0], acc[0]);
    acc[1] = mfma32(a, wf[s][1], acc[1]);
  }
#pragma unroll
  for (int reg = 0; reg < 16; ++reg) {
    int row = r0 + (reg & 3) + 8 * (reg >> 2) + 4 * hi;
    float a0 = acc[0][reg] + bia[0] + b2f(res[(size_t)row * 64 + lo]);
    float a1 = acc[1][reg] + bia[1] + b2f(res[(size_t)row * 64 + 32 + lo]);
    float su = a0 + a1, sq = a0 * a0 + a1 * a1;
#pragma unroll
    for (int m = 1; m <= 16; m <<= 1) { su += __shfl_xor(su, m); sq += __shfl_xor(sq, m); }
    float mean = su * (1.f / 64.f);
    float var = sq * (1.f / 64.f) - mean * mean;
    float rstd = rsqrtf(var + 1e-5f);
    out[(size_t)row * 64 + lo] = f2b((a0 - mean) * rstd * gg[0] + bb[0]);
    out[(size_t)row * 64 + 32 + lo] = f2b((a1 - mean) * rstd * gg[1] + bb[1]);
  }
}

// ---------------------------------------------------------------------------
// Fused FFN: LN(gelu(A@W1+b1)@W2 + b2 + A).  Wave = 32 rows, H kept in regs.
__global__ __launch_bounds__(256) void k_ffn(
    const u16* __restrict__ A, const u16* __restrict__ W1T, const u16* __restrict__ W2T,
    const float* __restrict__ b1, const float* __restrict__ b2,
    const float* __restrict__ g, const float* __restrict__ be,
    u16* __restrict__ outb, float* __restrict__ outf) {
  int t = threadIdx.x, w = t >> 6, lane = t & 63;
  int lo = lane & 31, hi = lane >> 5;
  int unit = blockIdx.x * 4 + w;
  int r0 = unit * 32;
  bf16x8 xf[4];
#pragma unroll
  for (int s = 0; s < 4; ++s) xf[s] = ldb8(&A[(size_t)(r0 + lo) * 64 + s * 16 + hi * 8]);
  f32x16 oacc[2] = {};
#pragma unroll
  for (int ft = 0; ft < 8; ++ft) {
    f32x16 hacc = {};
#pragma unroll
    for (int s = 0; s < 4; ++s)
      hacc = mfma32(ldb8(&W1T[((ft * 4 + s) * 64 + lane) * 8]), xf[s], hacc);
    float4 bb[4];
#pragma unroll
    for (int g4 = 0; g4 < 4; ++g4)
      bb[g4] = *reinterpret_cast<const float4*>(&b1[ft * 32 + g4 * 8 + 4 * hi]);
    float e[16];
#pragma unroll
    for (int r = 0; r < 16; ++r) {
      float z = hacc[r] + bb[r >> 2][r & 3];
      e[r] = 0.5f * z * (1.f + erff(z * 0.7071067811865475f));
    }
#pragma unroll
    for (int c = 0; c < 2; ++c) {
      unsigned Aw = cvtpk(e[c * 8 + 0], e[c * 8 + 1]);
      unsigned Bw = cvtpk(e[c * 8 + 2], e[c * 8 + 3]);
      unsigned Cw = cvtpk(e[c * 8 + 4], e[c * 8 + 5]);
      unsigned Dw = cvtpk(e[c * 8 + 6], e[c * 8 + 7]);
      swap32(Aw, Cw);
      swap32(Bw, Dw);
      uint4v pk; pk.x = Aw; pk.y = Bw; pk.z = Cw; pk.w = Dw;
      bf16x8 pf = __builtin_bit_cast(bf16x8, pk);
#pragma unroll
      for (int dt = 0; dt < 2; ++dt)
        oacc[dt] = mfma32(ldb8(&W2T[((dt * 16 + ft * 2 + c) * 64 + lane) * 8]), pf, oacc[dt]);
    }
  }
  int n = r0 + lo;
  float su = 0.f, sq = 0.f;
#pragma unroll
  for (int dt = 0; dt < 2; ++dt) {
#pragma unroll
    for (int m4 = 0; m4 < 4; ++m4) {
      int d0 = dt * 32 + m4 * 8 + 4 * hi;
      u16x4 rv = *reinterpret_cast<const u16x4*>(&A[(size_t)n * 64 + d0]);
      float4 b2v = *reinterpret_cast<const float4*>(&b2[d0]);
#pragma unroll
      for (int j = 0; j < 4; ++j) {
        int r = m4 * 4 + j;
        float val = oacc[dt][r] + b2v[j] + b2f(rv[j]);
        oacc[dt][r] = val;
        su += val; sq += val * val;
      }
    }
  }
  su += __shfl_xor(su, 32);
  sq += __shfl_xor(sq, 32);
  float mean = su * (1.f / 64.f);
  float var = sq * (1.f / 64.f) - mean * mean;
  float rstd = rsqrtf(var + 1e-5f);
#pragma unroll
  for (int dt = 0; dt < 2; ++dt) {
#pragma unroll
    for (int m4 = 0; m4 < 4; ++m4) {
      int d0 = dt * 32 + m4 * 8 + 4 * hi;
      float4 gv = *reinterpret_cast<const float4*>(&g[d0]);
      float4 bv = *reinterpret_cast<const float4*>(&be[d0]);
      float q0 = (oacc[dt][m4 * 4 + 0] - mean) * rstd * gv.x + bv.x;
      float q1 = (oacc[dt][m4 * 4 + 1] - mean) * rstd * gv.y + bv.y;
      float q2 = (oacc[dt][m4 * 4 + 2] - mean) * rstd * gv.z + bv.z;
      float q3 = (oacc[dt][m4 * 4 + 3] - mean) * rstd * gv.w + bv.w;
      if (outb) {
        unsigned w0 = cvtpk(q0, q1), w1 = cvtpk(q2, q3);
        u16x4 st = __builtin_bit_cast(u16x4, make_uint2(w0, w1));
        *reinterpret_cast<u16x4*>(&outb[(size_t)n * 64 + d0]) = st;
      }
      if (outf) {
        *reinterpret_cast<float4*>(&outf[(size_t)n * 64 + d0]) = make_float4(q0, q1, q2, q3);
      }
    }
  }
}

// ---------------------------------------------------------------------------
extern "C" void kernel_launch(void* const* d_in, const int* in_sizes, int n_in,
                              void* d_out, int out_size, void* d_ws, size_t ws_size,
                              hipStream_t stream) {
  const float* expr = (const float*)d_in[0];
  const float* emb  = (const float*)d_in[1];
  const float* Wq   = (const float*)d_in[2];
  const float* Wk   = (const float*)d_in[3];
  const float* Wv   = (const float*)d_in[4];
  const float* projK = (const float*)d_in[5];
  const float* projV = (const float*)d_in[6];
  const float* Wo   = (const float*)d_in[7];
  const float* bo   = (const float*)d_in[8];
  const float* g1   = (const float*)d_in[9];
  const float* be1  = (const float*)d_in[10];
  const float* W1   = (const float*)d_in[11];
  const float* bf1  = (const float*)d_in[12];
  const float* W2   = (const float*)d_in[13];
  const float* bf2  = (const float*)d_in[14];
  const float* g2   = (const float*)d_in[15];
  const float* be2  = (const float*)d_in[16];
  float* out = (float*)d_out;
  char* ws = (char*)d_ws;

  // workspace layout (bytes)
  u16* xb0 = (u16*)(ws + 0);                 // 10,240,000
  u16* xb1 = (u16*)(ws + 10240000);          // 10,240,000
  u16* xb2 = (u16*)(ws + 20480000);          // 10,240,000
  u16* qb  = (u16*)(ws + 30720000);          // 10,240,000
  u16* aob = (u16*)(ws + 40960000);          // 10,240,000
  float* part = (float*)(ws + 51200000);     // 20,971,520
  u16* pKT = (u16*)(ws + 92160000);          // 20,480,000 (2 layers)
  u16* pVT = (u16*)(ws + 112640000);         // 20,480,000
  u16* xTb = (u16*)(ws + 133120000);         // 10,240,000
  u16* kB  = (u16*)(ws + 143360000);         // 131,072
  u16* vTB = (u16*)(ws + 143491072);         // 131,072
  u16* wb  = (u16*)(ws + 143622144);         // 163,840
  u16* ones = (u16*)(ws + 143785984);        // 512 (bf16 1.0 x256)

  k_pre<<<5077, 256, 0, stream>>>(expr, emb, Wq, Wo, W1, W2, projK, projV,
                                  wb, pKT, pVT, xb0, ones);

  const u16* xin = xb0;
  for (int l = 0; l < 2; ++l) {
    const u16* wbq = wb + l * 4096;
    const u16* wbo = wb + 8192 + l * 4096;
    const u16* wb1 = wb + 16384 + l * 16384;
    const u16* wb2 = wb + 49152 + l * 16384;
    k_qxt<<<1253, 256, 0, stream>>>(xin, wbq, qb, xTb);
    k_proj<<<dim3(40, NB, 2), 256, 0, stream>>>(xTb, pKT + (size_t)l * KK * NN, pVT + (size_t)l * KK * NN, part);
    k_p2<<<dim3(32, NB, 2), 256, 0, stream>>>(part, Wk + l * 4096, Wv + l * 4096, kB, vTB);
    k_attn<<<dim3(625, NB), 256, 0, stream>>>(qb, kB, vTB, ones, aob);
    k_oln<<<625, 256, 0, stream>>>(aob, wbo, bo + l * 64, xin, g1 + l * 64, be1 + l * 64, xb1);
    k_ffn<<<625, 256, 0, stream>>>(xb1, wb1, wb2, bf1 + l * 256, bf2 + l * 64,
                                   g2 + l * 64, be2 + l * 64,
                                   l == 0 ? xb2 : nullptr, l == 1 ? out : nullptr);
    xin = xb2;
  }
}